// Round 4
// baseline (943.546 us; speedup 1.0000x reference)
//
#include <hip/hip_runtime.h>
#include <cstdint>
#include <cstddef>

// ---------------------------------------------------------------------------
// HybridLayer on MI355X (gfx950).
//   fp32 router (exact top-k via rank) -> gather+LN1 -> bf16-MFMA m_in GEMM
//   (u | silu(res) epilogue) -> algebraic sp elimination (g=(u.wB)(u.wC),
//   fused with y, in-place into resb) -> m_out GEMM (tok+=) -> fused LN2+MoE
//   router -> grouped sparse MoE (batched over blockIdx.z when ws allows,
//   per-expert loop fallback) -> fused out-write (+ load-balance loss).
// Sparse MoE: ~68.7 GF vs reference's dense 275 GF.
// ~16 graph nodes in batched mode (launch tail latency is first-order here).
// ---------------------------------------------------------------------------

typedef __bf16 bf16;
typedef bf16 bf16x4 __attribute__((ext_vector_type(4)));
typedef bf16 bf16x8 __attribute__((ext_vector_type(8)));
typedef float f32x4 __attribute__((ext_vector_type(4)));

#define DEV __device__ __forceinline__

constexpr int BB   = 2;
constexpr int S    = 2048;
constexpr int D    = 1024;
constexpr int KSEL = 1024;        // k = S*CAP
constexpr int NTOK = BB * KSEL;   // 2048
constexpr int INNER = 2048;
constexpr int HID  = 4096;        // 4*D
constexpr int NE   = 8;
constexpr float EPSF = 1e-5f;

DEV void gload_lds16(const void* g, void* l) {
  __builtin_amdgcn_global_load_lds(
      (const __attribute__((address_space(1))) void*)g,
      (__attribute__((address_space(3))) void*)l, 16, 0, 0);
}

DEV float wave_red_sum(float v) {
#pragma unroll
  for (int o = 32; o > 0; o >>= 1) v += __shfl_xor(v, o, 64);
  return v;
}

// Fused prep (1 node instead of 4): counters zero, wB/wC from xproj, cpack.
// blocks 0..7: wB/wC (2048 dims). blocks 8..47: cpack (INNER*5 floats).
__global__ __launch_bounds__(256)
void prep_kernel(const float* __restrict__ xp, float* __restrict__ wB,
                 float* __restrict__ wC, const float* __restrict__ convw,
                 const float* __restrict__ convb, float* __restrict__ cpack,
                 int* __restrict__ ecnt, int* __restrict__ fill,
                 float* __restrict__ cnt, int* __restrict__ zeroi) {
  int bid = blockIdx.x, t = threadIdx.x;
  if (bid == 0) {
    if (t < 8) { ecnt[t] = 0; fill[t] = 0; }
    if (t < 16) cnt[t] = 0.f;
    if (t == 0) zeroi[0] = 0;
  }
  if (bid < 8) {
    int d = bid * 256 + t;
    const float* r = xp + (size_t)d * 33;
    float s = 0.f;
#pragma unroll
    for (int j = 16; j < 32; j++) s += r[j];
    wB[d] = s;        // sum of xproj cols 16..31  (Bv.sum(-1) weights)
    wC[d] = r[32];    // xproj col 32              (Cv weights)
  } else {
    int i = (bid - 8) * 256 + t;  // 0..10239 = INNER*5
    cpack[i] = (i < INNER * 4) ? convw[i] : convb[i - INNER * 4];
  }
}

// fp32->bf16 transposed convert: in [R][C] fp32 -> out [C][R] bf16.
// blockIdx.z selects an expert slab of R*C elements (z=0 for single weights).
__global__ __launch_bounds__(256)
void convT_kernel(const float* __restrict__ in, bf16* __restrict__ out, int R, int C) {
  in  += (size_t)blockIdx.z * R * C;
  out += (size_t)blockIdx.z * R * C;
  __shared__ float t[32][33];
  int c0 = blockIdx.x * 32, r0 = blockIdx.y * 32;
  int tx = threadIdx.x & 31, ty = threadIdx.x >> 5;
#pragma unroll
  for (int i = 0; i < 4; i++) {
    int r = ty + i * 8;
    t[r][tx] = in[(size_t)(r0 + r) * C + c0 + tx];
  }
  __syncthreads();
#pragma unroll
  for (int i = 0; i < 4; i++) {
    int c = ty + i * 8;
    out[(size_t)(c0 + c) * R + r0 + tx] = (bf16)t[tx][c];
  }
}

// Router scores, fp32 throughout (exact top-k parity).
// 8 tokens x 256 hidden per block; 512 blocks => 2 blocks/CU.
__global__ __launch_bounds__(256)
void score_kernel(const float* __restrict__ x, const float* __restrict__ w1,
                  const float* __restrict__ b1, const float* __restrict__ w2,
                  const float* __restrict__ b2, float* __restrict__ scores) {
  __shared__ float As[8][8];       // [k][m]
  __shared__ float Bsh[8][256];    // [k][h]
  __shared__ float red[8][64];
  int tid = threadIdx.x;
  int m0 = blockIdx.x * 8;
  int tj = tid & 63, tm = tid >> 6;
  float acc[2][4] = {};
  for (int k0 = 0; k0 < 1024; k0 += 8) {
    if (tid < 64) {
      int r = tid >> 3, kk = tid & 7;
      As[kk][r] = x[(size_t)(m0 + r) * 1024 + k0 + kk];
    }
    {
      int kk = tid >> 5, j0 = (tid & 31) * 8;
      const float4* src = (const float4*)&w1[(size_t)(k0 + kk) * 256 + j0];
      float4 v0 = src[0], v1 = src[1];
      *(float4*)&Bsh[kk][j0] = v0;
      *(float4*)&Bsh[kk][j0 + 4] = v1;
    }
    __syncthreads();
#pragma unroll
    for (int k = 0; k < 8; k++) {
      float2 a = *(const float2*)&As[k][tm * 2];
      float4 bq = *(const float4*)&Bsh[k][tj * 4];
      acc[0][0] += a.x * bq.x; acc[0][1] += a.x * bq.y;
      acc[0][2] += a.x * bq.z; acc[0][3] += a.x * bq.w;
      acc[1][0] += a.y * bq.x; acc[1][1] += a.y * bq.y;
      acc[1][2] += a.y * bq.z; acc[1][3] += a.y * bq.w;
    }
    __syncthreads();
  }
  float4 b1v = *(const float4*)&b1[tj * 4];
  float4 w2v = *(const float4*)&w2[tj * 4];
  float b1a[4] = {b1v.x, b1v.y, b1v.z, b1v.w};
  float w2a[4] = {w2v.x, w2v.y, w2v.z, w2v.w};
#pragma unroll
  for (int i = 0; i < 2; i++) {
    float pacc = 0.f;
#pragma unroll
    for (int j = 0; j < 4; j++) {
      float h = fmaxf(acc[i][j] + b1a[j], 0.f);
      pacc += h * w2a[j];
    }
    red[tm * 2 + i][tj] = pacc;
  }
  __syncthreads();
  if (tid < 8) {
    float s = 0.f;
    for (int q = 0; q < 64; q++) s += red[tid][q];
    scores[m0 + tid] = s + b2[0];  // TEMP == 1.0
  }
}

// Exact rank (jax.lax.top_k tie semantics): rank = #{> or (== with lower idx)}
__global__ __launch_bounds__(256)
void rank_kernel(const float* __restrict__ scores, int* __restrict__ rnk) {
  int b = blockIdx.x >> 5, grp = blockIdx.x & 31;
  __shared__ float sc[2048];
  __shared__ int part[64][4];
  const float* s = scores + b * 2048;
  for (int i = threadIdx.x; i < 2048; i += 256) sc[i] = s[i];
  __syncthreads();
  int tq = threadIdx.x & 63, qr = threadIdx.x >> 6;
  int idx = grp * 64 + tq;
  float v = sc[idx];
  int c = 0;
  for (int i = qr * 512; i < qr * 512 + 512; i++) {
    float o = sc[i];
    c += (o > v) || (o == v && i < idx);
  }
  part[tq][qr] = c;
  __syncthreads();
  if (qr == 0) rnk[b * 2048 + idx] = part[tq][0] + part[tq][1] + part[tq][2] + part[tq][3];
}

// Select + prefix-scan + rank-order softmax weights + inverse maps.
// postok[b*S+s] = position of token s among selected (ascending-idx order);
// wtok[b*S+s]   = wsh[position]  -- replicates the reference's POSITIONAL
// pairing of rank-ordered w with ascending sorted_idx.
__global__ __launch_bounds__(1024)
void select_scan_kernel(const float* __restrict__ scores, const int* __restrict__ rnk,
                        int* __restrict__ sidx, int* __restrict__ postok,
                        float* __restrict__ wtok) {
  int b = blockIdx.x, t = threadIdx.x;
  const float* sc = scores + b * 2048;
  const int* rk = rnk + b * 2048;
  __shared__ int ts[1024];
  __shared__ float sbr[1024];   // score by rank
  __shared__ float wsh[1024];   // weight by rank
  __shared__ float reds[16];
  int r0 = rk[2 * t], r1 = rk[2 * t + 1];
  int f0 = (r0 < KSEL), f1 = (r1 < KSEL);
  if (f0) sbr[r0] = sc[2 * t];
  if (f1) sbr[r1] = sc[2 * t + 1];
  ts[t] = f0 + f1;
  __syncthreads();
  for (int off = 1; off < 1024; off <<= 1) {
    int add = (t >= off) ? ts[t - off] : 0;
    __syncthreads();
    ts[t] += add;
    __syncthreads();
  }
  int excl = ts[t] - (f0 + f1);
  if (f0) sidx[b * KSEL + excl] = 2 * t;
  if (f1) sidx[b * KSEL + excl + f0] = 2 * t + 1;
  float mx = sbr[0];  // rank 0 = max
  float ev = expf(sbr[t] - mx);
  float spart = wave_red_sum(ev);
  int wv = t >> 6, ln_ = t & 63;
  if (ln_ == 0) reds[wv] = spart;
  __syncthreads();
  float tot = 0.f;
#pragma unroll
  for (int q = 0; q < 16; q++) tot += reds[q];
  wsh[t] = ev / tot;
  __syncthreads();
  if (f0) { postok[b * S + 2 * t]     = excl;      wtok[b * S + 2 * t]     = wsh[excl]; }
  if (f1) { postok[b * S + 2 * t + 1] = excl + f0; wtok[b * S + 2 * t + 1] = wsh[excl + f0]; }
}

// Gather + LN1: tok = raw gathered x rows; nb = bf16(LN1(tok)).
__global__ __launch_bounds__(256)
void gather_ln1_kernel(const float* __restrict__ x, const int* __restrict__ sidx,
                       const float* __restrict__ w, const float* __restrict__ b,
                       float* __restrict__ tok, bf16* __restrict__ nb) {
  int i = blockIdx.x, t = threadIdx.x;
  int b_ = i >> 10;
  int s = sidx[i];
  const float* row = x + ((size_t)b_ * S + s) * D;
  float4 v = ((const float4*)row)[t];
  float s1 = v.x + v.y + v.z + v.w;
  float s2 = v.x * v.x + v.y * v.y + v.z * v.z + v.w * v.w;
  s1 = wave_red_sum(s1);
  s2 = wave_red_sum(s2);
  __shared__ float rs[8];
  int wv = t >> 6, ln_ = t & 63;
  if (ln_ == 0) { rs[wv] = s1; rs[4 + wv] = s2; }
  __syncthreads();
  float S1 = rs[0] + rs[1] + rs[2] + rs[3];
  float S2 = rs[4] + rs[5] + rs[6] + rs[7];
  float mu = S1 * (1.f / 1024.f);
  float var = S2 * (1.f / 1024.f) - mu * mu;
  float rstd = rsqrtf(var + EPSF);
  float4 wv4 = ((const float4*)w)[t], bv4 = ((const float4*)b)[t];
  float4 o;
  o.x = (v.x - mu) * rstd * wv4.x + bv4.x;
  o.y = (v.y - mu) * rstd * wv4.y + bv4.y;
  o.z = (v.z - mu) * rstd * wv4.z + bv4.z;
  o.w = (v.w - mu) * rstd * wv4.w + bv4.w;
  ((float4*)(tok + (size_t)i * D))[t] = v;
  bf16x4 ov = {(bf16)o.x, (bf16)o.y, (bf16)o.z, (bf16)o.w};
  *(bf16x4*)(nb + (size_t)i * D + t * 4) = ov;
}

// bf16 MFMA GEMM C=A@Bt^T, 128x128x(BK=32), m97-style global_load_lds staging.
// MODE 0: uv epilogue (u = c*convw3+convb | resb = bf16(silu(c)))
// MODE 1: tok += c
// MODE 2: MoE GEMM1 (A rows gathered via al_tok), h1[hoff+row] = bf16(gelu(c+b1e))
// MODE 3: MoE GEMM2 (A rows = h1[hoff+row]), atomicAdd(tok[al_tok], al_w*(c+b2e))
// MODE>=2 use blockIdx.z as expert index (z=0 + strides 0 for loop fallback).
template <int MODE>
__global__ __launch_bounds__(256)
void gemm_bt(const bf16* __restrict__ A, const bf16* __restrict__ Bt,
             int M, int N, int K,
             float* __restrict__ of, bf16* __restrict__ ob,
             const float* __restrict__ e0,
             const int* __restrict__ me_p, const int* __restrict__ poff_p,
             const int* __restrict__ hoff_p,
             const int* __restrict__ al_tok, const float* __restrict__ al_w,
             size_t bt_zstride, int e0_zstride) {
  int Me = M, base = 0, hoff = 0;
  if (MODE >= 2) {
    int z = blockIdx.z;
    Me = me_p[z];
    base = poff_p[z];
    hoff = hoff_p[z];
    Bt += (size_t)z * bt_zstride;
    e0 += (size_t)z * e0_zstride;
    if ((int)blockIdx.y * 128 >= Me) return;  // uniform early exit
  }
  __shared__ bf16 As[128 * 32];
  __shared__ bf16 Bs[128 * 32];
  const int tid = threadIdx.x, lane = tid & 63, wv = tid >> 6;
  const int m0 = blockIdx.y * 128, n0 = blockIdx.x * 128;

  const int srow = lane >> 2, sq = lane & 3;
  const int ra0 = wv * 32 + srow, ra1 = ra0 + 16;
  const bf16 *ap0, *ap1;
  if (MODE == 2) {
    int r0 = m0 + ra0, r1 = m0 + ra1;
    int t0 = (r0 < Me) ? al_tok[base + r0] : 0;  // clamp padding rows
    int t1 = (r1 < Me) ? al_tok[base + r1] : 0;
    ap0 = A + (size_t)t0 * K;
    ap1 = A + (size_t)t1 * K;
  } else if (MODE == 3) {
    ap0 = A + (size_t)(hoff + m0 + ra0) * K;
    ap1 = A + (size_t)(hoff + m0 + ra1) * K;
  } else {
    ap0 = A + (size_t)(m0 + ra0) * K;
    ap1 = A + (size_t)(m0 + ra1) * K;
  }
  const bf16* bp0 = Bt + (size_t)(n0 + ra0) * K;
  const bf16* bp1 = Bt + (size_t)(n0 + ra1) * K;

  bf16* lda0 = As + ((size_t)wv * 128 + lane) * 8;
  bf16* lda1 = As + ((size_t)wv * 128 + 64 + lane) * 8;
  bf16* ldb0 = Bs + ((size_t)wv * 128 + lane) * 8;
  bf16* ldb1 = Bs + ((size_t)wv * 128 + 64 + lane) * 8;

  const int g = lane >> 4, r16 = lane & 15;
  const int wr = (wv >> 1) * 64, wc = (wv & 1) * 64;

  f32x4 acc[4][4] = {};

  for (int k0 = 0; k0 < K; k0 += 32) {
    gload_lds16(ap0 + k0 + sq * 8, lda0);
    gload_lds16(ap1 + k0 + sq * 8, lda1);
    gload_lds16(bp0 + k0 + sq * 8, ldb0);
    gload_lds16(bp1 + k0 + sq * 8, ldb1);
    __syncthreads();  // drains vmcnt -> LDS ready
    bf16x8 av[4], bv[4];
#pragma unroll
    for (int m = 0; m < 4; m++)
      av[m] = *(const bf16x8*)&As[(wr + m * 16 + r16) * 32 + g * 8];
#pragma unroll
    for (int n = 0; n < 4; n++)
      bv[n] = *(const bf16x8*)&Bs[(wc + n * 16 + r16) * 32 + g * 8];
#pragma unroll
    for (int m = 0; m < 4; m++)
#pragma unroll
      for (int n = 0; n < 4; n++)
        acc[m][n] = __builtin_amdgcn_mfma_f32_16x16x32_bf16(av[m], bv[n], acc[m][n], 0, 0, 0);
    __syncthreads();
  }

#pragma unroll
  for (int m = 0; m < 4; m++) {
#pragma unroll
    for (int n = 0; n < 4; n++) {
#pragma unroll
      for (int j = 0; j < 4; j++) {
        int lr = wr + m * 16 + g * 4 + j;  // C/D: row=(lane>>4)*4+reg (m89)
        int lc = wc + n * 16 + r16;        //      col=lane&15
        float c = acc[m][n][j];
        int grow = m0 + lr, gcol = n0 + lc;
        if (MODE == 0) {
          if (gcol < INNER) {
            of[(size_t)grow * INNER + gcol] = c * e0[gcol * 4 + 3] + e0[INNER * 4 + gcol];
          } else {
            float sg = c / (1.f + expf(-c));
            ob[(size_t)grow * INNER + (gcol - INNER)] = (bf16)sg;
          }
        } else if (MODE == 1) {
          of[(size_t)grow * D + gcol] += c;
        } else if (MODE == 2) {
          if (grow < Me) {
            float z = c + e0[gcol];
            float gl = 0.5f * z * (1.f + erff(z * 0.70710678118654752f));
            ob[(size_t)(hoff + grow) * HID + gcol] = (bf16)gl;
          }
        } else {
          if (grow < Me) {
            int tk = al_tok[base + grow];
            float w_ = al_w[base + grow];
            atomicAdd(&of[(size_t)tk * D + gcol], w_ * (c + e0[gcol]));
          }
        }
      }
    }
  }
}

// Fused: g = (u.wB)*(u.wC); resb <- bf16(u * g * resb)   (y in place)
__global__ __launch_bounds__(256)
void gdot_y_kernel(const float* __restrict__ u, bf16* __restrict__ resb,
                   const float* __restrict__ wB, const float* __restrict__ wC) {
  int i = blockIdx.x, t = threadIdx.x;
  const float4* ur = (const float4*)(u + (size_t)i * INNER);
  float4 u0 = ur[t], u1 = ur[t + 256];
  float4 b0 = ((const float4*)wB)[t], b1v = ((const float4*)wB)[t + 256];
  float4 c0 = ((const float4*)wC)[t], c1v = ((const float4*)wC)[t + 256];
  float dB = u0.x * b0.x + u0.y * b0.y + u0.z * b0.z + u0.w * b0.w
           + u1.x * b1v.x + u1.y * b1v.y + u1.z * b1v.z + u1.w * b1v.w;
  float dC = u0.x * c0.x + u0.y * c0.y + u0.z * c0.z + u0.w * c0.w
           + u1.x * c1v.x + u1.y * c1v.y + u1.z * c1v.z + u1.w * c1v.w;
  dB = wave_red_sum(dB);
  dC = wave_red_sum(dC);
  __shared__ float rs[8];
  __shared__ float gs;
  int wv = t >> 6, ln_ = t & 63;
  if (ln_ == 0) { rs[wv] = dB; rs[4 + wv] = dC; }
  __syncthreads();
  if (t == 0) gs = (rs[0] + rs[1] + rs[2] + rs[3]) * (rs[4] + rs[5] + rs[6] + rs[7]);
  __syncthreads();
  float g = gs;
  bf16x4* rp = (bf16x4*)resb + (size_t)i * 512;
  bf16x4 s0 = rp[t], s1 = rp[t + 256];
  bf16x4 y0 = {(bf16)(u0.x * g * (float)s0[0]), (bf16)(u0.y * g * (float)s0[1]),
               (bf16)(u0.z * g * (float)s0[2]), (bf16)(u0.w * g * (float)s0[3])};
  bf16x4 y1 = {(bf16)(u1.x * g * (float)s1[0]), (bf16)(u1.y * g * (float)s1[1]),
               (bf16)(u1.z * g * (float)s1[2]), (bf16)(u1.w * g * (float)s1[3])};
  rp[t] = y0;
  rp[t + 256] = y1;
}

// Fused LN2 + MoE router top-2. Reads tok row, writes nb row, routing outputs.
__global__ __launch_bounds__(256)
void ln2_route_kernel(const float* __restrict__ tok, const float* __restrict__ w,
                      const float* __restrict__ b, const float* __restrict__ rwt,
                      const float* __restrict__ rb, bf16* __restrict__ nb,
                      int* __restrict__ sel_e, float* __restrict__ rwo,
                      int* __restrict__ ecnt, float* __restrict__ cnt) {
  int n = blockIdx.x, t = threadIdx.x;
  float4 v = ((const float4*)(tok + (size_t)n * D))[t];
  float s1 = v.x + v.y + v.z + v.w;
  float s2 = v.x * v.x + v.y * v.y + v.z * v.z + v.w * v.w;
  s1 = wave_red_sum(s1);
  s2 = wave_red_sum(s2);
  __shared__ float rs[8];
  __shared__ float lp[4][8];
  __shared__ float lg[8];
  int wv = t >> 6, ln_ = t & 63;
  if (ln_ == 0) { rs[wv] = s1; rs[4 + wv] = s2; }
  __syncthreads();
  float S1 = rs[0] + rs[1] + rs[2] + rs[3];
  float S2 = rs[4] + rs[5] + rs[6] + rs[7];
  float mu = S1 * (1.f / 1024.f);
  float var = S2 * (1.f / 1024.f) - mu * mu;
  float rstd = rsqrtf(var + EPSF);
  float4 wv4 = ((const float4*)w)[t], bv4 = ((const float4*)b)[t];
  float oc[4];
  oc[0] = (v.x - mu) * rstd * wv4.x + bv4.x;
  oc[1] = (v.y - mu) * rstd * wv4.y + bv4.y;
  oc[2] = (v.z - mu) * rstd * wv4.z + bv4.z;
  oc[3] = (v.w - mu) * rstd * wv4.w + bv4.w;
  bf16x4 ov = {(bf16)oc[0], (bf16)oc[1], (bf16)oc[2], (bf16)oc[3]};
  *(bf16x4*)(nb + (size_t)n * D + t * 4) = ov;
  // routing logits: thread covers dims 4t..4t+3, rwt row-major [D][8]
  float part[8] = {};
  const float4* wr4 = (const float4*)(rwt + (size_t)t * 32);
#pragma unroll
  for (int c = 0; c < 4; c++) {
    float4 ra = wr4[2 * c], rbq = wr4[2 * c + 1];
    part[0] += oc[c] * ra.x;  part[1] += oc[c] * ra.y;
    part[2] += oc[c] * ra.z;  part[3] += oc[c] * ra.w;
    part[4] += oc[c] * rbq.x; part[5] += oc[c] * rbq.y;
    part[6] += oc[c] * rbq.z; part[7] += oc[c] * rbq.w;
  }
#pragma unroll
  for (int e = 0; e < 8; e++) part[e] = wave_red_sum(part[e]);
  if (ln_ == 0)
#pragma unroll
    for (int e = 0; e < 8; e++) lp[wv][e] = part[e];
  __syncthreads();
  if (t == 0) {
#pragma unroll
    for (int e = 0; e < 8; e++) lg[e] = rb[e] + lp[0][e] + lp[1][e] + lp[2][e] + lp[3][e];
    float mx = lg[0];
    for (int q = 1; q < 8; q++) mx = fmaxf(mx, lg[q]);
    float p[8];
    float sm = 0.f;
    for (int q = 0; q < 8; q++) { p[q] = expf(lg[q] - mx); sm += p[q]; }
    float inv = 1.f / sm;
    for (int q = 0; q < 8; q++) p[q] *= inv;
    int e0 = 0;
    for (int q = 1; q < 8; q++) if (p[q] > p[e0]) e0 = q;   // tie -> lowest idx
    int e1 = (e0 == 0) ? 1 : 0;
    for (int q = 0; q < 8; q++) if (q != e0 && p[q] > p[e1]) e1 = q;
    float r0 = p[e0], r1 = p[e1], iS = 1.f / (r0 + r1);
    sel_e[n * 2] = e0;
    sel_e[n * 2 + 1] = e1;
    rwo[n * 2] = r0 * iS;
    rwo[n * 2 + 1] = r1 * iS;
    atomicAdd(&ecnt[e0], 1);
    atomicAdd(&ecnt[e1], 1);
    atomicAdd(&cnt[e0], 1.f);      // one_hot(sel_e,E).sum(0) is (2,E)
    atomicAdd(&cnt[8 + e1], 1.f);
  }
}

__global__ void offs_lb_kernel(const int* __restrict__ ecnt, int* __restrict__ poff,
                               const float* __restrict__ cnt, float* __restrict__ lb_out) {
  if (threadIdx.x == 0 && blockIdx.x == 0) {
    int o = 0;
    for (int e = 0; e < NE; e++) {
      poff[e] = o;
      o += (ecnt[e] + 127) & ~127;  // 128-aligned per-expert segments
    }
    float mu = 0.f;
    for (int i = 0; i < 16; i++) mu += cnt[i];
    mu *= (1.f / 16.f);
    float v = 0.f;
    for (int i = 0; i < 16; i++) { float d_ = cnt[i] - mu; v += d_ * d_; }
    v *= (1.f / 15.f);  // ddof=1
    lb_out[0] = v / mu * 0.01f;
  }
}

__global__ void scatter_assign_kernel(const int* __restrict__ sel_e, const float* __restrict__ rw,
                                      const int* __restrict__ poff, int* __restrict__ fill,
                                      int* __restrict__ al_tok, float* __restrict__ al_w) {
  int a = blockIdx.x * 256 + threadIdx.x;
  if (a < NTOK * 2) {
    int n = a >> 1;
    int e = sel_e[a];
    int pzn = atomicAdd(&fill[e], 1);
    int r = poff[e] + pzn;
    al_tok[r] = n;
    al_w[r] = rw[a];
  }
}

// Final output: every row written (selected rows = tok*weight, rest = x copy).
__global__ __launch_bounds__(256)
void outwrite_kernel(const float* __restrict__ x, const float* __restrict__ tok,
                     const int* __restrict__ rnk, const int* __restrict__ postok,
                     const float* __restrict__ wtok, float* __restrict__ out) {
  int r = blockIdx.x, t = threadIdx.x;
  int b = r >> 11;  // S == 2048
  float4 o;
  if (rnk[r] < KSEL) {
    int pos = postok[r];
    float w = wtok[r];
    float4 v = ((const float4*)(tok + ((size_t)b * KSEL + pos) * D))[t];
    o.x = v.x * w; o.y = v.y * w; o.z = v.z * w; o.w = v.w * w;
  } else {
    o = ((const float4*)(x + (size_t)r * D))[t];
  }
  ((float4*)(out + (size_t)r * D))[t] = o;
}

// ---------------------------------------------------------------------------
extern "C" void kernel_launch(void* const* d_in, const int* in_sizes, int n_in,
                              void* d_out, int out_size, void* d_ws, size_t ws_size,
                              hipStream_t stream) {
  (void)in_sizes; (void)n_in; (void)out_size;
  const float* x      = (const float*)d_in[0];
  const float* ln1w   = (const float*)d_in[1];
  const float* ln1b   = (const float*)d_in[2];
  const float* ln2w   = (const float*)d_in[3];
  const float* ln2b   = (const float*)d_in[4];
  const float* mrw1   = (const float*)d_in[5];
  const float* mrb1   = (const float*)d_in[6];
  const float* mrw2   = (const float*)d_in[7];
  const float* mrb2   = (const float*)d_in[8];
  const float* minw   = (const float*)d_in[9];
  const float* mconvw = (const float*)d_in[10];  // [INNER][4]
  const float* mconvb = (const float*)d_in[11];  // [INNER]
  const float* mxproj = (const float*)d_in[12];  // [INNER][33]
  const float* moutw  = (const float*)d_in[13];
  const float* merw   = (const float*)d_in[14];
  const float* merb   = (const float*)d_in[15];
  const float* mew1   = (const float*)d_in[16];
  const float* meb1   = (const float*)d_in[17];
  const float* mew2   = (const float*)d_in[18];
  const float* meb2   = (const float*)d_in[19];
  float* out = (float*)d_out;

  // Batched MoE needs ~204.5 MB of ws; gate with a small margin.
  const bool big = ws_size >= (size_t)206 * 1024 * 1024;

  char* p = (char*)d_ws;
  auto take = [&](size_t bytes) {
    char* r = p;
    p += (bytes + 255) & ~(size_t)255;
    return r;
  };
  float* scores = (float*)take(4096 * 4);
  int*   rnk    = (int*)take(4096 * 4);
  int*   sidx   = (int*)take(2048 * 4);
  int*   postok = (int*)take(4096 * 4);
  float* wtok   = (float*)take(4096 * 4);
  float* wB     = (float*)take(2048 * 4);
  float* wC     = (float*)take(2048 * 4);
  int*   ecnt   = (int*)take(8 * 4);
  int*   fill   = (int*)take(8 * 4);
  int*   poff   = (int*)take(8 * 4);
  int*   zeroi  = (int*)take(8 * 4);
  float* cnt    = (float*)take(16 * 4);
  int*   sel_e  = (int*)take(NTOK * 2 * 4);
  float* rwsel  = (float*)take(NTOK * 2 * 4);
  int*   altok  = (int*)take(5120 * 4);
  float* alw    = (float*)take(5120 * 4);
  float* cpack  = (float*)take((size_t)(INNER * 4 + INNER) * 4);  // convw | convb
  float* tok    = (float*)take((size_t)NTOK * D * 4);             // 8 MB
  bf16*  nb     = (bf16*)take((size_t)NTOK * D * 2);              // 4 MB
  float* u      = (float*)take((size_t)NTOK * INNER * 4);         // 16 MB
  bf16*  resb   = (bf16*)take((size_t)NTOK * INNER * 2);          // 8 MB (silu(res) -> y)
  bf16*  h1     = (bf16*)take((size_t)(big ? 5120 : 2048) * HID * 2);
  bf16*  wTA    = (bf16*)take((size_t)(big ? NE : 1) * HID * D * 2);
  bf16*  wTB    = (bf16*)take((size_t)(big ? NE : 1) * HID * D * 2);
  // loop mode ~52 MB; batched ~204.5 MB

  // prep: counters + wB/wC + cpack (one node)
  prep_kernel<<<48, 256, 0, stream>>>(mxproj, wB, wC, mconvw, mconvb, cpack,
                                      ecnt, fill, cnt, zeroi);

  // router (fp32, exact top-k)
  score_kernel<<<512, 256, 0, stream>>>(x, mrw1, mrb1, mrw2, mrb2, scores);
  rank_kernel<<<64, 256, 0, stream>>>(scores, rnk);
  select_scan_kernel<<<BB, 1024, 0, stream>>>(scores, rnk, sidx, postok, wtok);

  // gather + LN1
  gather_ln1_kernel<<<NTOK, 256, 0, stream>>>(x, sidx, ln1w, ln1b, tok, nb);

  // m_in GEMM: uv = n1 @ m_in_w -> u | silu(res)
  convT_kernel<<<dim3(128, 32, 1), 256, 0, stream>>>(minw, wTA, D, 2 * INNER);
  gemm_bt<0><<<dim3(32, 16, 1), 256, 0, stream>>>(nb, wTA, NTOK, 2 * INNER, D,
                                                  u, resb, cpack,
                                                  nullptr, nullptr, nullptr, nullptr, nullptr,
                                                  0, 0);

  // g + y (in place into resb)
  gdot_y_kernel<<<NTOK, 256, 0, stream>>>(u, resb, wB, wC);

  // m_out GEMM: tok += y @ m_out_w
  convT_kernel<<<dim3(32, 64, 1), 256, 0, stream>>>(moutw, wTB, INNER, D);
  gemm_bt<1><<<dim3(8, 16, 1), 256, 0, stream>>>(resb, wTB, NTOK, D, INNER,
                                                 tok, nullptr, nullptr,
                                                 nullptr, nullptr, nullptr, nullptr, nullptr,
                                                 0, 0);

  // fused LN2 + routing
  ln2_route_kernel<<<NTOK, 256, 0, stream>>>(tok, ln2w, ln2b, merw, merb,
                                             nb, sel_e, rwsel, ecnt, cnt);
  offs_lb_kernel<<<1, 64, 0, stream>>>(ecnt, poff, cnt, out + (size_t)BB * S * D);
  scatter_assign_kernel<<<16, 256, 0, stream>>>(sel_e, rwsel, poff, fill, altok, alw);

  if (big) {
    // batched over blockIdx.z: 4 launches for the whole MoE
    convT_kernel<<<dim3(128, 32, NE), 256, 0, stream>>>(mew1, wTA, D, HID);
    gemm_bt<2><<<dim3(32, 16, NE), 256, 0, stream>>>(nb, wTA, NTOK, HID, D,
                                                     nullptr, h1, meb1,
                                                     ecnt, poff, poff, altok, alw,
                                                     (size_t)HID * D, HID);
    convT_kernel<<<dim3(32, 128, NE), 256, 0, stream>>>(mew2, wTB, HID, D);
    gemm_bt<3><<<dim3(8, 16, NE), 256, 0, stream>>>(h1, wTB, NTOK, D, HID,
                                                    tok, nullptr, meb2,
                                                    ecnt, poff, poff, altok, alw,
                                                    (size_t)D * HID, D);
  } else {
    for (int e = 0; e < NE; e++) {
      convT_kernel<<<dim3(128, 32, 1), 256, 0, stream>>>(mew1 + (size_t)e * D * HID, wTA, D, HID);
      gemm_bt<2><<<dim3(32, 16, 1), 256, 0, stream>>>(nb, wTA, NTOK, HID, D,
                                                      nullptr, h1, meb1 + (size_t)e * HID,
                                                      ecnt + e, poff + e, zeroi, altok, alw,
                                                      0, 0);
      convT_kernel<<<dim3(32, 128, 1), 256, 0, stream>>>(mew2 + (size_t)e * HID * D, wTB, HID, D);
      gemm_bt<3><<<dim3(8, 16, 1), 256, 0, stream>>>(h1, wTB, NTOK, D, HID,
                                                     tok, nullptr, meb2 + (size_t)e * D,
                                                     ecnt + e, poff + e, zeroi, altok, alw,
                                                     0, 0);
    }
  }

  // final output (full coverage); lb already written by offs_lb_kernel
  outwrite_kernel<<<BB * S, 256, 0, stream>>>(x, tok, rnk, postok, wtok, out);
}

// Round 6
// 908.521 us; speedup vs baseline: 1.0386x; 1.0386x over previous
//
#include <hip/hip_runtime.h>
#include <cstdint>
#include <cstddef>

// ---------------------------------------------------------------------------
// HybridLayer on MI355X (gfx950).
//   fp32 router (exact top-k via rank) -> gather+LN1 -> bf16-MFMA m_in GEMM
//   (u | silu(res) epilogue) -> algebraic sp elimination (g=(u.wB)(u.wC),
//   fused with y, in-place into resb) -> m_out GEMM (tok+=) -> fused LN2+MoE
//   router -> grouped sparse MoE (batched over expert dim when ws allows) ->
//   fused out-write (+ load-balance loss).
// R4 counters: gemm_bt ~190us, MfmaUtil 7.7%, HBM 13%, Occ 11% => latency-
// bound single-buffered K-loop (issue->wait serial stall every K-step).
// R6 (single change vs R4): 2-phase prefetch K-loop -- double-buffered LDS,
// raw s_barrier + asm vmcnt(0), tile t+1 staged under tile t's MFMA.
// XCD swizzle from R5 draft REVERTED: pinning expert e to XCD e makes the
// 8MB B-panel thrash the 4MB L2 (desk calc: 256MB fetch vs 180 measured);
// default round-robin already gives ~3MB/XCD concurrent working set.
// ---------------------------------------------------------------------------

typedef __bf16 bf16;
typedef bf16 bf16x4 __attribute__((ext_vector_type(4)));
typedef bf16 bf16x8 __attribute__((ext_vector_type(8)));
typedef float f32x4 __attribute__((ext_vector_type(4)));

#define DEV __device__ __forceinline__

constexpr int BB   = 2;
constexpr int S    = 2048;
constexpr int D    = 1024;
constexpr int KSEL = 1024;        // k = S*CAP
constexpr int NTOK = BB * KSEL;   // 2048
constexpr int INNER = 2048;
constexpr int HID  = 4096;        // 4*D
constexpr int NE   = 8;
constexpr float EPSF = 1e-5f;

DEV void gload_lds16(const void* g, void* l) {
  __builtin_amdgcn_global_load_lds(
      (const __attribute__((address_space(1))) void*)g,
      (__attribute__((address_space(3))) void*)l, 16, 0, 0);
}

DEV float wave_red_sum(float v) {
#pragma unroll
  for (int o = 32; o > 0; o >>= 1) v += __shfl_xor(v, o, 64);
  return v;
}

// Fused prep (1 node): counters zero, wB/wC from xproj, cpack.
__global__ __launch_bounds__(256)
void prep_kernel(const float* __restrict__ xp, float* __restrict__ wB,
                 float* __restrict__ wC, const float* __restrict__ convw,
                 const float* __restrict__ convb, float* __restrict__ cpack,
                 int* __restrict__ ecnt, int* __restrict__ fill,
                 float* __restrict__ cnt, int* __restrict__ zeroi) {
  int bid = blockIdx.x, t = threadIdx.x;
  if (bid == 0) {
    if (t < 8) { ecnt[t] = 0; fill[t] = 0; }
    if (t < 16) cnt[t] = 0.f;
    if (t == 0) zeroi[0] = 0;
  }
  if (bid < 8) {
    int d = bid * 256 + t;
    const float* r = xp + (size_t)d * 33;
    float s = 0.f;
#pragma unroll
    for (int j = 16; j < 32; j++) s += r[j];
    wB[d] = s;        // sum of xproj cols 16..31  (Bv.sum(-1) weights)
    wC[d] = r[32];    // xproj col 32              (Cv weights)
  } else {
    int i = (bid - 8) * 256 + t;  // 0..10239 = INNER*5
    cpack[i] = (i < INNER * 4) ? convw[i] : convb[i - INNER * 4];
  }
}

// fp32->bf16 transposed convert: in [R][C] fp32 -> out [C][R] bf16.
__global__ __launch_bounds__(256)
void convT_kernel(const float* __restrict__ in, bf16* __restrict__ out, int R, int C) {
  in  += (size_t)blockIdx.z * R * C;
  out += (size_t)blockIdx.z * R * C;
  __shared__ float t[32][33];
  int c0 = blockIdx.x * 32, r0 = blockIdx.y * 32;
  int tx = threadIdx.x & 31, ty = threadIdx.x >> 5;
#pragma unroll
  for (int i = 0; i < 4; i++) {
    int r = ty + i * 8;
    t[r][tx] = in[(size_t)(r0 + r) * C + c0 + tx];
  }
  __syncthreads();
#pragma unroll
  for (int i = 0; i < 4; i++) {
    int c = ty + i * 8;
    out[(size_t)(c0 + c) * R + r0 + tx] = (bf16)t[tx][c];
  }
}

// Router scores, fp32 throughout (exact top-k parity). 8 tokens/block.
__global__ __launch_bounds__(256)
void score_kernel(const float* __restrict__ x, const float* __restrict__ w1,
                  const float* __restrict__ b1, const float* __restrict__ w2,
                  const float* __restrict__ b2, float* __restrict__ scores) {
  __shared__ float As[8][8];       // [k][m]
  __shared__ float Bsh[8][256];    // [k][h]
  __shared__ float red[8][64];
  int tid = threadIdx.x;
  int m0 = blockIdx.x * 8;
  int tj = tid & 63, tm = tid >> 6;
  float acc[2][4] = {};
  for (int k0 = 0; k0 < 1024; k0 += 8) {
    if (tid < 64) {
      int r = tid >> 3, kk = tid & 7;
      As[kk][r] = x[(size_t)(m0 + r) * 1024 + k0 + kk];
    }
    {
      int kk = tid >> 5, j0 = (tid & 31) * 8;
      const float4* src = (const float4*)&w1[(size_t)(k0 + kk) * 256 + j0];
      float4 v0 = src[0], v1 = src[1];
      *(float4*)&Bsh[kk][j0] = v0;
      *(float4*)&Bsh[kk][j0 + 4] = v1;
    }
    __syncthreads();
#pragma unroll
    for (int k = 0; k < 8; k++) {
      float2 a = *(const float2*)&As[k][tm * 2];
      float4 bq = *(const float4*)&Bsh[k][tj * 4];
      acc[0][0] += a.x * bq.x; acc[0][1] += a.x * bq.y;
      acc[0][2] += a.x * bq.z; acc[0][3] += a.x * bq.w;
      acc[1][0] += a.y * bq.x; acc[1][1] += a.y * bq.y;
      acc[1][2] += a.y * bq.z; acc[1][3] += a.y * bq.w;
    }
    __syncthreads();
  }
  float4 b1v = *(const float4*)&b1[tj * 4];
  float4 w2v = *(const float4*)&w2[tj * 4];
  float b1a[4] = {b1v.x, b1v.y, b1v.z, b1v.w};
  float w2a[4] = {w2v.x, w2v.y, w2v.z, w2v.w};
#pragma unroll
  for (int i = 0; i < 2; i++) {
    float pacc = 0.f;
#pragma unroll
    for (int j = 0; j < 4; j++) {
      float h = fmaxf(acc[i][j] + b1a[j], 0.f);
      pacc += h * w2a[j];
    }
    red[tm * 2 + i][tj] = pacc;
  }
  __syncthreads();
  if (tid < 8) {
    float s = 0.f;
    for (int q = 0; q < 64; q++) s += red[tid][q];
    scores[m0 + tid] = s + b2[0];  // TEMP == 1.0
  }
}

// Exact rank (jax.lax.top_k tie semantics): rank = #{> or (== with lower idx)}
__global__ __launch_bounds__(256)
void rank_kernel(const float* __restrict__ scores, int* __restrict__ rnk) {
  int b = blockIdx.x >> 5, grp = blockIdx.x & 31;
  __shared__ float sc[2048];
  __shared__ int part[64][4];
  const float* s = scores + b * 2048;
  for (int i = threadIdx.x; i < 2048; i += 256) sc[i] = s[i];
  __syncthreads();
  int tq = threadIdx.x & 63, qr = threadIdx.x >> 6;
  int idx = grp * 64 + tq;
  float v = sc[idx];
  int c = 0;
  for (int i = qr * 512; i < qr * 512 + 512; i++) {
    float o = sc[i];
    c += (o > v) || (o == v && i < idx);
  }
  part[tq][qr] = c;
  __syncthreads();
  if (qr == 0) rnk[b * 2048 + idx] = part[tq][0] + part[tq][1] + part[tq][2] + part[tq][3];
}

// Select + prefix-scan + rank-order softmax weights + inverse maps.
__global__ __launch_bounds__(1024)
void select_scan_kernel(const float* __restrict__ scores, const int* __restrict__ rnk,
                        int* __restrict__ sidx, int* __restrict__ postok,
                        float* __restrict__ wtok) {
  int b = blockIdx.x, t = threadIdx.x;
  const float* sc = scores + b * 2048;
  const int* rk = rnk + b * 2048;
  __shared__ int ts[1024];
  __shared__ float sbr[1024];   // score by rank
  __shared__ float wsh[1024];   // weight by rank
  __shared__ float reds[16];
  int r0 = rk[2 * t], r1 = rk[2 * t + 1];
  int f0 = (r0 < KSEL), f1 = (r1 < KSEL);
  if (f0) sbr[r0] = sc[2 * t];
  if (f1) sbr[r1] = sc[2 * t + 1];
  ts[t] = f0 + f1;
  __syncthreads();
  for (int off = 1; off < 1024; off <<= 1) {
    int add = (t >= off) ? ts[t - off] : 0;
    __syncthreads();
    ts[t] += add;
    __syncthreads();
  }
  int excl = ts[t] - (f0 + f1);
  if (f0) sidx[b * KSEL + excl] = 2 * t;
  if (f1) sidx[b * KSEL + excl + f0] = 2 * t + 1;
  float mx = sbr[0];  // rank 0 = max
  float ev = expf(sbr[t] - mx);
  float spart = wave_red_sum(ev);
  int wv = t >> 6, ln_ = t & 63;
  if (ln_ == 0) reds[wv] = spart;
  __syncthreads();
  float tot = 0.f;
#pragma unroll
  for (int q = 0; q < 16; q++) tot += reds[q];
  wsh[t] = ev / tot;
  __syncthreads();
  if (f0) { postok[b * S + 2 * t]     = excl;      wtok[b * S + 2 * t]     = wsh[excl]; }
  if (f1) { postok[b * S + 2 * t + 1] = excl + f0; wtok[b * S + 2 * t + 1] = wsh[excl + f0]; }
}

// Gather + LN1: tok = raw gathered x rows; nb = bf16(LN1(tok)).
__global__ __launch_bounds__(256)
void gather_ln1_kernel(const float* __restrict__ x, const int* __restrict__ sidx,
                       const float* __restrict__ w, const float* __restrict__ b,
                       float* __restrict__ tok, bf16* __restrict__ nb) {
  int i = blockIdx.x, t = threadIdx.x;
  int b_ = i >> 10;
  int s = sidx[i];
  const float* row = x + ((size_t)b_ * S + s) * D;
  float4 v = ((const float4*)row)[t];
  float s1 = v.x + v.y + v.z + v.w;
  float s2 = v.x * v.x + v.y * v.y + v.z * v.z + v.w * v.w;
  s1 = wave_red_sum(s1);
  s2 = wave_red_sum(s2);
  __shared__ float rs[8];
  int wv = t >> 6, ln_ = t & 63;
  if (ln_ == 0) { rs[wv] = s1; rs[4 + wv] = s2; }
  __syncthreads();
  float S1 = rs[0] + rs[1] + rs[2] + rs[3];
  float S2 = rs[4] + rs[5] + rs[6] + rs[7];
  float mu = S1 * (1.f / 1024.f);
  float var = S2 * (1.f / 1024.f) - mu * mu;
  float rstd = rsqrtf(var + EPSF);
  float4 wv4 = ((const float4*)w)[t], bv4 = ((const float4*)b)[t];
  float4 o;
  o.x = (v.x - mu) * rstd * wv4.x + bv4.x;
  o.y = (v.y - mu) * rstd * wv4.y + bv4.y;
  o.z = (v.z - mu) * rstd * wv4.z + bv4.z;
  o.w = (v.w - mu) * rstd * wv4.w + bv4.w;
  ((float4*)(tok + (size_t)i * D))[t] = v;
  bf16x4 ov = {(bf16)o.x, (bf16)o.y, (bf16)o.z, (bf16)o.w};
  *(bf16x4*)(nb + (size_t)i * D + t * 4) = ov;
}

// bf16 MFMA GEMM C=A@Bt^T, 128x128x(BK=32), 2-phase prefetch (dbuf LDS,
// raw s_barrier + asm vmcnt(0); loads for tile t+1 fly under MFMA of tile t).
// MODE 0: uv epilogue (u = c*convw3+convb | resb = bf16(silu(c)))
// MODE 1: tok += c
// MODE 2: MoE GEMM1 (A rows via al_tok), h1[hoff+row] = bf16(gelu(c+b1e))
// MODE 3: MoE GEMM2 (A rows = h1[hoff+row]), atomicAdd(tok[al_tok], al_w*(c+b2e))
template <int MODE>
__global__ __launch_bounds__(256)
void gemm_bt(const bf16* __restrict__ A, const bf16* __restrict__ Bt,
             int M, int N, int K,
             float* __restrict__ of, bf16* __restrict__ ob,
             const float* __restrict__ e0,
             const int* __restrict__ me_p, const int* __restrict__ poff_p,
             const int* __restrict__ hoff_p,
             const int* __restrict__ al_tok, const float* __restrict__ al_w,
             size_t bt_zstride, int e0_zstride) {
  const int bx = blockIdx.x, by = blockIdx.y, bz = blockIdx.z;
  int Me = M, base = 0, hoff = 0;
  if (MODE >= 2) {
    Me = me_p[bz];
    base = poff_p[bz];
    hoff = hoff_p[bz];
    Bt += (size_t)bz * bt_zstride;
    e0 += (size_t)bz * e0_zstride;
    if (by * 128 >= Me) return;  // uniform early exit
  }
  __shared__ bf16 As[2][128 * 32];
  __shared__ bf16 Bs[2][128 * 32];
  const int tid = threadIdx.x, lane = tid & 63, wv = tid >> 6;
  const int m0 = by * 128, n0 = bx * 128;

  const int srow = lane >> 2, sq = lane & 3;
  const int ra0 = wv * 32 + srow, ra1 = ra0 + 16;
  const bf16 *ap0, *ap1;
  if (MODE == 2) {
    int r0 = m0 + ra0, r1 = m0 + ra1;
    int t0 = (r0 < Me) ? al_tok[base + r0] : 0;  // clamp padding rows
    int t1 = (r1 < Me) ? al_tok[base + r1] : 0;
    ap0 = A + (size_t)t0 * K;
    ap1 = A + (size_t)t1 * K;
  } else if (MODE == 3) {
    ap0 = A + (size_t)(hoff + m0 + ra0) * K;
    ap1 = A + (size_t)(hoff + m0 + ra1) * K;
  } else {
    ap0 = A + (size_t)(m0 + ra0) * K;
    ap1 = A + (size_t)(m0 + ra1) * K;
  }
  const bf16* bp0 = Bt + (size_t)(n0 + ra0) * K;
  const bf16* bp1 = Bt + (size_t)(n0 + ra1) * K;

  const int soff0 = (wv * 128 + lane) * 8;
  const int soff1 = (wv * 128 + 64 + lane) * 8;
  const int koff = sq * 8;

  const int g = lane >> 4, r16 = lane & 15;
  const int wr = (wv >> 1) * 64, wc = (wv & 1) * 64;

  f32x4 acc[4][4] = {};

  auto stage = [&](int buf, int k0) {
    gload_lds16(ap0 + k0 + koff, &As[buf][soff0]);
    gload_lds16(ap1 + k0 + koff, &As[buf][soff1]);
    gload_lds16(bp0 + k0 + koff, &Bs[buf][soff0]);
    gload_lds16(bp1 + k0 + koff, &Bs[buf][soff1]);
  };

  const int nk = K >> 5;
  stage(0, 0);
  asm volatile("s_waitcnt vmcnt(0)" ::: "memory");
  __builtin_amdgcn_s_barrier();

  for (int t = 0; t < nk; t++) {
    const int cur = t & 1;
    if (t + 1 < nk) stage(cur ^ 1, (t + 1) * 32);   // prefetch flies under MFMA
    bf16x8 av[4], bv[4];
#pragma unroll
    for (int m = 0; m < 4; m++)
      av[m] = *(const bf16x8*)&As[cur][(wr + m * 16 + r16) * 32 + g * 8];
#pragma unroll
    for (int n = 0; n < 4; n++)
      bv[n] = *(const bf16x8*)&Bs[cur][(wc + n * 16 + r16) * 32 + g * 8];
#pragma unroll
    for (int m = 0; m < 4; m++)
#pragma unroll
      for (int n = 0; n < 4; n++)
        acc[m][n] = __builtin_amdgcn_mfma_f32_16x16x32_bf16(av[m], bv[n], acc[m][n], 0, 0, 0);
    asm volatile("s_waitcnt vmcnt(0)" ::: "memory");  // prefetch tail only
    __builtin_amdgcn_s_barrier();                     // all reads of cur done
  }

#pragma unroll
  for (int m = 0; m < 4; m++) {
#pragma unroll
    for (int n = 0; n < 4; n++) {
#pragma unroll
      for (int j = 0; j < 4; j++) {
        int lr = wr + m * 16 + g * 4 + j;  // C/D: row=(lane>>4)*4+reg (m89)
        int lc = wc + n * 16 + r16;        //      col=lane&15
        float c = acc[m][n][j];
        int grow = m0 + lr, gcol = n0 + lc;
        if (MODE == 0) {
          if (gcol < INNER) {
            of[(size_t)grow * INNER + gcol] = c * e0[gcol * 4 + 3] + e0[INNER * 4 + gcol];
          } else {
            float sg = c / (1.f + expf(-c));
            ob[(size_t)grow * INNER + (gcol - INNER)] = (bf16)sg;
          }
        } else if (MODE == 1) {
          of[(size_t)grow * D + gcol] += c;
        } else if (MODE == 2) {
          if (grow < Me) {
            float z = c + e0[gcol];
            float gl = 0.5f * z * (1.f + erff(z * 0.70710678118654752f));
            ob[(size_t)(hoff + grow) * HID + gcol] = (bf16)gl;
          }
        } else {
          if (grow < Me) {
            int tk = al_tok[base + grow];
            float w_ = al_w[base + grow];
            atomicAdd(&of[(size_t)tk * D + gcol], w_ * (c + e0[gcol]));
          }
        }
      }
    }
  }
}

// Fused: g = (u.wB)*(u.wC); resb <- bf16(u * g * resb)   (y in place)
__global__ __launch_bounds__(256)
void gdot_y_kernel(const float* __restrict__ u, bf16* __restrict__ resb,
                   const float* __restrict__ wB, const float* __restrict__ wC) {
  int i = blockIdx.x, t = threadIdx.x;
  const float4* ur = (const float4*)(u + (size_t)i * INNER);
  float4 u0 = ur[t], u1 = ur[t + 256];
  float4 b0 = ((const float4*)wB)[t], b1v = ((const float4*)wB)[t + 256];
  float4 c0 = ((const float4*)wC)[t], c1v = ((const float4*)wC)[t + 256];
  float dB = u0.x * b0.x + u0.y * b0.y + u0.z * b0.z + u0.w * b0.w
           + u1.x * b1v.x + u1.y * b1v.y + u1.z * b1v.z + u1.w * b1v.w;
  float dC = u0.x * c0.x + u0.y * c0.y + u0.z * c0.z + u0.w * c0.w
           + u1.x * c1v.x + u1.y * c1v.y + u1.z * c1v.z + u1.w * c1v.w;
  dB = wave_red_sum(dB);
  dC = wave_red_sum(dC);
  __shared__ float rs[8];
  __shared__ float gs;
  int wv = t >> 6, ln_ = t & 63;
  if (ln_ == 0) { rs[wv] = dB; rs[4 + wv] = dC; }
  __syncthreads();
  if (t == 0) gs = (rs[0] + rs[1] + rs[2] + rs[3]) * (rs[4] + rs[5] + rs[6] + rs[7]);
  __syncthreads();
  float g = gs;
  bf16x4* rp = (bf16x4*)resb + (size_t)i * 512;
  bf16x4 s0 = rp[t], s1 = rp[t + 256];
  bf16x4 y0 = {(bf16)(u0.x * g * (float)s0[0]), (bf16)(u0.y * g * (float)s0[1]),
               (bf16)(u0.z * g * (float)s0[2]), (bf16)(u0.w * g * (float)s0[3])};
  bf16x4 y1 = {(bf16)(u1.x * g * (float)s1[0]), (bf16)(u1.y * g * (float)s1[1]),
               (bf16)(u1.z * g * (float)s1[2]), (bf16)(u1.w * g * (float)s1[3])};
  rp[t] = y0;
  rp[t + 256] = y1;
}

// Fused LN2 + MoE router top-2.
__global__ __launch_bounds__(256)
void ln2_route_kernel(const float* __restrict__ tok, const float* __restrict__ w,
                      const float* __restrict__ b, const float* __restrict__ rwt,
                      const float* __restrict__ rb, bf16* __restrict__ nb,
                      int* __restrict__ sel_e, float* __restrict__ rwo,
                      int* __restrict__ ecnt, float* __restrict__ cnt) {
  int n = blockIdx.x, t = threadIdx.x;
  float4 v = ((const float4*)(tok + (size_t)n * D))[t];
  float s1 = v.x + v.y + v.z + v.w;
  float s2 = v.x * v.x + v.y * v.y + v.z * v.z + v.w * v.w;
  s1 = wave_red_sum(s1);
  s2 = wave_red_sum(s2);
  __shared__ float rs[8];
  __shared__ float lp[4][8];
  __shared__ float lg[8];
  int wv = t >> 6, ln_ = t & 63;
  if (ln_ == 0) { rs[wv] = s1; rs[4 + wv] = s2; }
  __syncthreads();
  float S1 = rs[0] + rs[1] + rs[2] + rs[3];
  float S2 = rs[4] + rs[5] + rs[6] + rs[7];
  float mu = S1 * (1.f / 1024.f);
  float var = S2 * (1.f / 1024.f) - mu * mu;
  float rstd = rsqrtf(var + EPSF);
  float4 wv4 = ((const float4*)w)[t], bv4 = ((const float4*)b)[t];
  float oc[4];
  oc[0] = (v.x - mu) * rstd * wv4.x + bv4.x;
  oc[1] = (v.y - mu) * rstd * wv4.y + bv4.y;
  oc[2] = (v.z - mu) * rstd * wv4.z + bv4.z;
  oc[3] = (v.w - mu) * rstd * wv4.w + bv4.w;
  bf16x4 ov = {(bf16)oc[0], (bf16)oc[1], (bf16)oc[2], (bf16)oc[3]};
  *(bf16x4*)(nb + (size_t)n * D + t * 4) = ov;
  float part[8] = {};
  const float4* wr4 = (const float4*)(rwt + (size_t)t * 32);
#pragma unroll
  for (int c = 0; c < 4; c++) {
    float4 ra = wr4[2 * c], rbq = wr4[2 * c + 1];
    part[0] += oc[c] * ra.x;  part[1] += oc[c] * ra.y;
    part[2] += oc[c] * ra.z;  part[3] += oc[c] * ra.w;
    part[4] += oc[c] * rbq.x; part[5] += oc[c] * rbq.y;
    part[6] += oc[c] * rbq.z; part[7] += oc[c] * rbq.w;
  }
#pragma unroll
  for (int e = 0; e < 8; e++) part[e] = wave_red_sum(part[e]);
  if (ln_ == 0)
#pragma unroll
    for (int e = 0; e < 8; e++) lp[wv][e] = part[e];
  __syncthreads();
  if (t == 0) {
#pragma unroll
    for (int e = 0; e < 8; e++) lg[e] = rb[e] + lp[0][e] + lp[1][e] + lp[2][e] + lp[3][e];
    float mx = lg[0];
    for (int q = 1; q < 8; q++) mx = fmaxf(mx, lg[q]);
    float p[8];
    float sm = 0.f;
    for (int q = 0; q < 8; q++) { p[q] = expf(lg[q] - mx); sm += p[q]; }
    float inv = 1.f / sm;
    for (int q = 0; q < 8; q++) p[q] *= inv;
    int e0 = 0;
    for (int q = 1; q < 8; q++) if (p[q] > p[e0]) e0 = q;   // tie -> lowest idx
    int e1 = (e0 == 0) ? 1 : 0;
    for (int q = 0; q < 8; q++) if (q != e0 && p[q] > p[e1]) e1 = q;
    float r0 = p[e0], r1 = p[e1], iS = 1.f / (r0 + r1);
    sel_e[n * 2] = e0;
    sel_e[n * 2 + 1] = e1;
    rwo[n * 2] = r0 * iS;
    rwo[n * 2 + 1] = r1 * iS;
    atomicAdd(&ecnt[e0], 1);
    atomicAdd(&ecnt[e1], 1);
    atomicAdd(&cnt[e0], 1.f);      // one_hot(sel_e,E).sum(0) is (2,E)
    atomicAdd(&cnt[8 + e1], 1.f);
  }
}

__global__ void offs_lb_kernel(const int* __restrict__ ecnt, int* __restrict__ poff,
                               const float* __restrict__ cnt, float* __restrict__ lb_out) {
  if (threadIdx.x == 0 && blockIdx.x == 0) {
    int o = 0;
    for (int e = 0; e < NE; e++) {
      poff[e] = o;
      o += (ecnt[e] + 127) & ~127;  // 128-aligned per-expert segments
    }
    float mu = 0.f;
    for (int i = 0; i < 16; i++) mu += cnt[i];
    mu *= (1.f / 16.f);
    float v = 0.f;
    for (int i = 0; i < 16; i++) { float d_ = cnt[i] - mu; v += d_ * d_; }
    v *= (1.f / 15.f);  // ddof=1
    lb_out[0] = v / mu * 0.01f;
  }
}

__global__ void scatter_assign_kernel(const int* __restrict__ sel_e, const float* __restrict__ rw,
                                      const int* __restrict__ poff, int* __restrict__ fill,
                                      int* __restrict__ al_tok, float* __restrict__ al_w) {
  int a = blockIdx.x * 256 + threadIdx.x;
  if (a < NTOK * 2) {
    int n = a >> 1;
    int e = sel_e[a];
    int pzn = atomicAdd(&fill[e], 1);
    int r = poff[e] + pzn;
    al_tok[r] = n;
    al_w[r] = rw[a];
  }
}

// Final output: every row written (selected rows = tok*weight, rest = x copy).
__global__ __launch_bounds__(256)
void outwrite_kernel(const float* __restrict__ x, const float* __restrict__ tok,
                     const int* __restrict__ rnk, const int* __restrict__ postok,
                     const float* __restrict__ wtok, float* __restrict__ out) {
  int r = blockIdx.x, t = threadIdx.x;
  int b = r >> 11;  // S == 2048
  float4 o;
  if (rnk[r] < KSEL) {
    int pos = postok[r];
    float w = wtok[r];
    float4 v = ((const float4*)(tok + ((size_t)b * KSEL + pos) * D))[t];
    o.x = v.x * w; o.y = v.y * w; o.z = v.z * w; o.w = v.w * w;
  } else {
    o = ((const float4*)(x + (size_t)r * D))[t];
  }
  ((float4*)(out + (size_t)r * D))[t] = o;
}

// ---------------------------------------------------------------------------
extern "C" void kernel_launch(void* const* d_in, const int* in_sizes, int n_in,
                              void* d_out, int out_size, void* d_ws, size_t ws_size,
                              hipStream_t stream) {
  (void)in_sizes; (void)n_in; (void)out_size;
  const float* x      = (const float*)d_in[0];
  const float* ln1w   = (const float*)d_in[1];
  const float* ln1b   = (const float*)d_in[2];
  const float* ln2w   = (const float*)d_in[3];
  const float* ln2b   = (const float*)d_in[4];
  const float* mrw1   = (const float*)d_in[5];
  const float* mrb1   = (const float*)d_in[6];
  const float* mrw2   = (const float*)d_in[7];
  const float* mrb2   = (const float*)d_in[8];
  const float* minw   = (const float*)d_in[9];
  const float* mconvw = (const float*)d_in[10];  // [INNER][4]
  const float* mconvb = (const float*)d_in[11];  // [INNER]
  const float* mxproj = (const float*)d_in[12];  // [INNER][33]
  const float* moutw  = (const float*)d_in[13];
  const float* merw   = (const float*)d_in[14];
  const float* merb   = (const float*)d_in[15];
  const float* mew1   = (const float*)d_in[16];
  const float* meb1   = (const float*)d_in[17];
  const float* mew2   = (const float*)d_in[18];
  const float* meb2   = (const float*)d_in[19];
  float* out = (float*)d_out;

  const bool big = ws_size >= (size_t)206 * 1024 * 1024;

  char* p = (char*)d_ws;
  auto take = [&](size_t bytes) {
    char* r = p;
    p += (bytes + 255) & ~(size_t)255;
    return r;
  };
  float* scores = (float*)take(4096 * 4);
  int*   rnk    = (int*)take(4096 * 4);
  int*   sidx   = (int*)take(2048 * 4);
  int*   postok = (int*)take(4096 * 4);
  float* wtok   = (float*)take(4096 * 4);
  float* wB     = (float*)take(2048 * 4);
  float* wC     = (float*)take(2048 * 4);
  int*   ecnt   = (int*)take(8 * 4);
  int*   fill   = (int*)take(8 * 4);
  int*   poff   = (int*)take(8 * 4);
  int*   zeroi  = (int*)take(8 * 4);
  float* cnt    = (float*)take(16 * 4);
  int*   sel_e  = (int*)take(NTOK * 2 * 4);
  float* rwsel  = (float*)take(NTOK * 2 * 4);
  int*   altok  = (int*)take(5120 * 4);
  float* alw    = (float*)take(5120 * 4);
  float* cpack  = (float*)take((size_t)(INNER * 4 + INNER) * 4);  // convw | convb
  float* tok    = (float*)take((size_t)NTOK * D * 4);             // 8 MB
  bf16*  nb     = (bf16*)take((size_t)NTOK * D * 2);              // 4 MB
  float* u      = (float*)take((size_t)NTOK * INNER * 4);         // 16 MB
  bf16*  resb   = (bf16*)take((size_t)NTOK * INNER * 2);          // 8 MB (silu(res) -> y)
  bf16*  h1     = (bf16*)take((size_t)(big ? 5120 : 2048) * HID * 2);
  bf16*  wTA    = (bf16*)take((size_t)(big ? NE : 1) * HID * D * 2);
  bf16*  wTB    = (bf16*)take((size_t)(big ? NE : 1) * HID * D * 2);

  // prep: counters + wB/wC + cpack (one node)
  prep_kernel<<<48, 256, 0, stream>>>(mxproj, wB, wC, mconvw, mconvb, cpack,
                                      ecnt, fill, cnt, zeroi);

  // router (fp32, exact top-k)
  score_kernel<<<512, 256, 0, stream>>>(x, mrw1, mrb1, mrw2, mrb2, scores);
  rank_kernel<<<64, 256, 0, stream>>>(scores, rnk);
  select_scan_kernel<<<BB, 1024, 0, stream>>>(scores, rnk, sidx, postok, wtok);

  // gather + LN1
  gather_ln1_kernel<<<NTOK, 256, 0, stream>>>(x, sidx, ln1w, ln1b, tok, nb);

  // m_in GEMM: uv = n1 @ m_in_w -> u | silu(res)
  convT_kernel<<<dim3(128, 32, 1), 256, 0, stream>>>(minw, wTA, D, 2 * INNER);
  gemm_bt<0><<<dim3(32, 16, 1), 256, 0, stream>>>(nb, wTA, NTOK, 2 * INNER, D,
                                                  u, resb, cpack,
                                                  nullptr, nullptr, nullptr, nullptr, nullptr,
                                                  0, 0);

  // g + y (in place into resb)
  gdot_y_kernel<<<NTOK, 256, 0, stream>>>(u, resb, wB, wC);

  // m_out GEMM: tok += y @ m_out_w
  convT_kernel<<<dim3(32, 64, 1), 256, 0, stream>>>(moutw, wTB, INNER, D);
  gemm_bt<1><<<dim3(8, 16, 1), 256, 0, stream>>>(resb, wTB, NTOK, D, INNER,
                                                 tok, nullptr, nullptr,
                                                 nullptr, nullptr, nullptr, nullptr, nullptr,
                                                 0, 0);

  // fused LN2 + routing
  ln2_route_kernel<<<NTOK, 256, 0, stream>>>(tok, ln2w, ln2b, merw, merb,
                                             nb, sel_e, rwsel, ecnt, cnt);
  offs_lb_kernel<<<1, 64, 0, stream>>>(ecnt, poff, cnt, out + (size_t)BB * S * D);
  scatter_assign_kernel<<<16, 256, 0, stream>>>(sel_e, rwsel, poff, fill, altok, alw);

  if (big) {
    // batched over expert dim: 4 launches for the whole MoE
    convT_kernel<<<dim3(128, 32, NE), 256, 0, stream>>>(mew1, wTA, D, HID);
    gemm_bt<2><<<dim3(32, 16, NE), 256, 0, stream>>>(nb, wTA, NTOK, HID, D,
                                                     nullptr, h1, meb1,
                                                     ecnt, poff, poff, altok, alw,
                                                     (size_t)HID * D, HID);
    convT_kernel<<<dim3(32, 128, NE), 256, 0, stream>>>(mew2, wTB, HID, D);
    gemm_bt<3><<<dim3(8, 16, NE), 256, 0, stream>>>(h1, wTB, NTOK, D, HID,
                                                    tok, nullptr, meb2,
                                                    ecnt, poff, poff, altok, alw,
                                                    (size_t)D * HID, D);
  } else {
    for (int e = 0; e < NE; e++) {
      convT_kernel<<<dim3(128, 32, 1), 256, 0, stream>>>(mew1 + (size_t)e * D * HID, wTA, D, HID);
      gemm_bt<2><<<dim3(32, 16, 1), 256, 0, stream>>>(nb, wTA, NTOK, HID, D,
                                                      nullptr, h1, meb1 + (size_t)e * HID,
                                                      ecnt + e, poff + e, zeroi, altok, alw,
                                                      0, 0);
      convT_kernel<<<dim3(32, 128, 1), 256, 0, stream>>>(mew2 + (size_t)e * HID * D, wTB, HID, D);
      gemm_bt<3><<<dim3(8, 16, 1), 256, 0, stream>>>(h1, wTB, NTOK, D, HID,
                                                     tok, nullptr, meb2 + (size_t)e * D,
                                                     ecnt + e, poff + e, zeroi, altok, alw,
                                                     0, 0);
    }
  }

  // final output (full coverage); lb already written by offs_lb_kernel
  outwrite_kernel<<<BB * S, 256, 0, stream>>>(x, tok, rnk, postok, wtok, out);
}